// Round 1
// baseline (2982.803 us; speedup 1.0000x reference)
//
#include <hip/hip_runtime.h>
#include <math.h>

#define KDIM 512
#define KD4  128      // KDIM/4
#define BM   64       // rows per block (4 waves x 16 rows)
#define BN   128      // cols per block (64 lanes x 2 cols)
#define BK   32
#define BK4  8        // BK/4
#define NSTAGES 16    // KDIM/BK
#define NCLS 1000
#define CUTOFF 3.0f
#define MAXCAP 4096

// ---- ordered-float <-> uint encoding for atomicMax on floats ----
__device__ __forceinline__ unsigned enc_f(float f) {
    unsigned u = __float_as_uint(f);
    return (u & 0x80000000u) ? ~u : (u | 0x80000000u);
}
__device__ __forceinline__ float dec_f(unsigned k) {
    unsigned u = (k & 0x80000000u) ? (k & 0x7FFFFFFFu) : ~k;
    return __uint_as_float(u);
}

__global__ void k_init(unsigned* __restrict__ cnt, unsigned* __restrict__ gmax, int B) {
    int i = blockIdx.x * blockDim.x + threadIdx.x;
    if (i < B) { cnt[i] = 0u; gmax[i] = enc_f(-3.0e38f); }
}

// GEMM (fp32) + per-row candidate collection.
// Block = 256 threads = 4 waves. Wave w handles rows [blockIdx.x*64 + w*16, +16).
// Lane handles cols colBase+lane and colBase+lane+64.
// A rows read via wave-uniform loads (s_load); B tile staged in LDS.
__global__ __launch_bounds__(256, 4) void k_gemm_collect(
    const float* __restrict__ A,     // [Brows][512]
    const float* __restrict__ Bt,    // [N][512]
    float* __restrict__ cand_val,
    int*   __restrict__ cand_idx,
    unsigned* __restrict__ cnt,
    unsigned* __restrict__ gmax,
    int N, int cap)
{
    // [col][9 float4] : stride 36 floats -> bank group (col+k4)&7, conflict-free
    __shared__ float4 Bs[BN * 9];

    const int tid  = threadIdx.x;
    const int lane = tid & 63;
    const int wid  = __builtin_amdgcn_readfirstlane(tid >> 6);
    const int rowBase = blockIdx.x * BM + wid * 16;
    const int colBase = blockIdx.y * BN;

    const float4* __restrict__ A4 = (const float4*)A + (size_t)rowBase * KD4; // uniform base
    const float4* __restrict__ B4 = (const float4*)Bt;

    float acc0[16], acc1[16];
#pragma unroll
    for (int r = 0; r < 16; ++r) { acc0[r] = 0.f; acc1[r] = 0.f; }

    const int lk4 = tid & 7;        // k4 slot this thread loads
    const int lc0 = tid >> 3;       // first col this thread loads (+32*i)

    for (int ks = 0; ks < NSTAGES; ++ks) {
        __syncthreads();
#pragma unroll
        for (int i = 0; i < 4; ++i) {
            int c = lc0 + i * 32;
            int gcol = colBase + c;
            float4 v = make_float4(0.f, 0.f, 0.f, 0.f);
            if (gcol < N) v = B4[(size_t)gcol * KD4 + ks * BK4 + lk4];
            Bs[c * 9 + lk4] = v;
        }
        __syncthreads();

#pragma unroll
        for (int k4 = 0; k4 < BK4; ++k4) {
            float4 b0 = Bs[lane * 9 + k4];
            float4 b1 = Bs[(lane + 64) * 9 + k4];
#pragma unroll
            for (int r = 0; r < 16; ++r) {
                float4 a = A4[r * KD4 + ks * BK4 + k4];   // uniform addr -> s_load
                acc0[r] += a.x * b0.x + a.y * b0.y + a.z * b0.z + a.w * b0.w;
                acc1[r] += a.x * b1.x + a.y * b1.y + a.z * b1.z + a.w * b1.w;
            }
        }
    }

    // ---- per-row chunk max, global running max, candidate append ----
#pragma unroll
    for (int r = 0; r < 16; ++r) {
        float m = fmaxf(acc0[r], acc1[r]);
#pragma unroll
        for (int off = 32; off > 0; off >>= 1) m = fmaxf(m, __shfl_xor(m, off));
        unsigned oldk = 0u;
        if (lane == 0) oldk = atomicMax(&gmax[rowBase + r], enc_f(m));
        oldk = (unsigned)__shfl((int)oldk, 0);
        float thr = fmaxf(dec_f(oldk), m) - CUTOFF;

        int c0 = colBase + lane, c1 = colBase + lane + 64;
        if (acc0[r] >= thr && c0 < N) {
            unsigned p = atomicAdd(&cnt[rowBase + r], 1u);
            if (p < (unsigned)cap) {
                cand_val[(size_t)(rowBase + r) * cap + p] = acc0[r];
                cand_idx[(size_t)(rowBase + r) * cap + p] = c0;
            }
        }
        if (acc1[r] >= thr && c1 < N) {
            unsigned p = atomicAdd(&cnt[rowBase + r], 1u);
            if (p < (unsigned)cap) {
                cand_val[(size_t)(rowBase + r) * cap + p] = acc1[r];
                cand_idx[(size_t)(rowBase + r) * cap + p] = c1;
            }
        }
    }
}

// One block per row: filter candidates >= rowmax - CUTOFF, sort desc, softmax,
// scatter into the 4 k-slices (anything below cutoff has weight < e^-43).
__global__ __launch_bounds__(256) void k_finalize(
    const float* __restrict__ cand_val,
    const int* __restrict__ cand_idx,
    const unsigned* __restrict__ cnt,
    const unsigned* __restrict__ gmax,
    const int* __restrict__ labels,
    float* __restrict__ out,
    int Brows, int cap)
{
    __shared__ float s_val[256];
    __shared__ int   s_idx[256];
    __shared__ int   s_n;
    const int row = blockIdx.x;
    const int tid = threadIdx.x;
    if (tid == 0) s_n = 0;
    __syncthreads();

    const float m   = dec_f(gmax[row]);
    const float thr = m - CUTOFF;
    const int n = min((int)cnt[row], cap);
    for (int i = tid; i < n; i += 256) {
        float v = cand_val[(size_t)row * cap + i];
        if (v >= thr) {
            int p = atomicAdd(&s_n, 1);
            if (p < 256) { s_val[p] = v; s_idx[p] = cand_idx[(size_t)row * cap + i]; }
        }
    }
    __syncthreads();

    // zero this row's 4 output slices
    for (int c = tid; c < 4 * NCLS; c += 256) {
        int s = c / NCLS, cc = c - s * NCLS;
        out[(size_t)s * ((size_t)Brows * NCLS) + (size_t)row * NCLS + cc] = 0.f;
    }
    __syncthreads();

    if (tid == 0) {
        int ns = min(s_n, 256);
        // insertion sort descending (ns is tiny, typically 1-5)
        for (int i = 1; i < ns; ++i) {
            float v = s_val[i]; int ix = s_idx[i];
            int j = i - 1;
            while (j >= 0 && s_val[j] < v) { s_val[j+1] = s_val[j]; s_idx[j+1] = s_idx[j]; --j; }
            s_val[j+1] = v; s_idx[j+1] = ix;
        }
        if (ns > 200) ns = 200;   // reference softmax spans exactly top-200
        float Z = 0.f;
        for (int i = 0; i < ns; ++i) Z += expf((s_val[i] - m) / 0.07f);
        float invZ = 1.f / Z;
        const int kv[4] = {10, 20, 100, 200};
        for (int i = 0; i < ns; ++i) {
            float w = expf((s_val[i] - m) / 0.07f) * invZ;
            int lab = labels[s_idx[i]];
#pragma unroll
            for (int s = 0; s < 4; ++s)
                if (i < kv[s])
                    out[(size_t)s * ((size_t)Brows * NCLS) + (size_t)row * NCLS + lab] += w;
        }
    }
}

extern "C" void kernel_launch(void* const* d_in, const int* in_sizes, int n_in,
                              void* d_out, int out_size, void* d_ws, size_t ws_size,
                              hipStream_t stream) {
    const float* A      = (const float*)d_in[0];   // (256, 512)
    const float* Bt     = (const float*)d_in[1];   // (100000, 512)
    const int*   labels = (const int*)d_in[2];     // (100000,)
    float* out = (float*)d_out;                    // (4, 256, 1000)

    const int Brows = in_sizes[0] / KDIM;          // 256
    const int N     = in_sizes[2];                 // 100000

    // workspace layout: cnt[Brows] | gmax[Brows] | cand_val[Brows*cap] | cand_idx[Brows*cap]
    size_t avail_pairs = (ws_size - (size_t)2 * Brows * 4) / ((size_t)Brows * 8);
    int cap = (int)(avail_pairs < (size_t)MAXCAP ? avail_pairs : (size_t)MAXCAP);
    if (cap < 1) cap = 1;

    unsigned* cnt  = (unsigned*)d_ws;
    unsigned* gmax = cnt + Brows;
    float* cand_val = (float*)(gmax + Brows);
    int*   cand_idx = (int*)(cand_val + (size_t)Brows * cap);

    k_init<<<(Brows + 255) / 256, 256, 0, stream>>>(cnt, gmax, Brows);

    dim3 grid((Brows + BM - 1) / BM, (N + BN - 1) / BN);  // x = row-tiles (fast) for B-tile L2 reuse
    k_gemm_collect<<<grid, 256, 0, stream>>>(A, Bt, cand_val, cand_idx, cnt, gmax, N, cap);

    k_finalize<<<Brows, 256, 0, stream>>>(cand_val, cand_idx, cnt, gmax, labels, out, Brows, cap);
}

// Round 2
// 398.280 us; speedup vs baseline: 7.4892x; 7.4892x over previous
//
#include <hip/hip_runtime.h>
#include <math.h>

#define KDIM   512
#define NCLS   1000
#define CUTOFF 3.0f
#define MAXCAP 4096
#define BN     64
#define BK     64
#define NSTAGE (KDIM / BK)   // 8

typedef __attribute__((ext_vector_type(8))) short  short8;
typedef __attribute__((ext_vector_type(4))) float  floatx4;

// ---- ordered-float <-> uint encoding for atomicMax on floats ----
__device__ __forceinline__ unsigned enc_f(float f) {
    unsigned u = __float_as_uint(f);
    return (u & 0x80000000u) ? ~u : (u | 0x80000000u);
}
__device__ __forceinline__ float dec_f(unsigned k) {
    unsigned u = (k & 0x80000000u) ? (k & 0x7FFFFFFFu) : ~k;
    return __uint_as_float(u);
}
// fp32 -> bf16 round-to-nearest-even
__device__ __forceinline__ unsigned short f2bf(float f) {
    unsigned u = __float_as_uint(f);
    u += 0x7FFFu + ((u >> 16) & 1u);
    return (unsigned short)(u >> 16);
}
__device__ __forceinline__ float bf2f(unsigned short h) {
    return __uint_as_float(((unsigned)h) << 16);
}

// Prep: init cnt/gmax; convert A (Brows x 512 fp32) into fragment-major bf16
// hi/lo: af slot (16B units) = ((s16*16 + c)*2 + h)*64 + lane,
// lane = kq*16 + (r&15), s16 = r>>4, c = k32-chunk, kq = k-octet within chunk.
__global__ void k_prep(const float* __restrict__ A, unsigned short* __restrict__ af,
                       unsigned* __restrict__ cnt, unsigned* __restrict__ gmax, int Brows) {
    int t = blockIdx.x * blockDim.x + threadIdx.x;
    if (t < Brows) { cnt[t] = 0u; gmax[t] = enc_f(-3.0e38f); }
    if (t >= Brows * (KDIM / 8)) return;
    int r = t >> 6;                 // row (64 k-octets per row)
    int o = t & 63;                 // k-octet index
    int s16 = r >> 4, c = o >> 2, kq = o & 3;
    int lane = kq * 16 + (r & 15);
    const float* src = A + (size_t)r * KDIM + o * 8;
    size_t bhi = ((size_t)((s16 * 16 + c) * 2 + 0) * 64 + lane) * 8;
    size_t blo = ((size_t)((s16 * 16 + c) * 2 + 1) * 64 + lane) * 8;
#pragma unroll
    for (int j = 0; j < 8; ++j) {
        float f = src[j];
        unsigned short h = f2bf(f);
        af[bhi + j] = h;
        af[blo + j] = f2bf(f - bf2f(h));
    }
}

// GEMM: block = 512 thr = 8 waves, covers ALL 256 rows (wave w: rows w*32..+32),
// BN=64 cols per block, full K=512 accumulation. Split-bf16 3-pass MFMA.
__global__ __launch_bounds__(512, 4) void k_gemm(
    const float* __restrict__ Bt,            // [N][512] fp32
    const unsigned short* __restrict__ af,   // A frags bf16 hi/lo
    float* __restrict__ cand_val, int* __restrict__ cand_idx,
    unsigned* __restrict__ cnt, unsigned* __restrict__ gmax,
    int N, int cap)
{
    __shared__ short8 BsH[512];   // 8 KB: [fid 0..7][64 lanes] 16B frag chunks
    __shared__ short8 BsL[512];

    const int tid  = threadIdx.x;
    const int lane = tid & 63;
    const int wid  = tid >> 6;                 // 0..7
    const int colBase = blockIdx.x * BN;

    // ---- B staging mapping: thread loads 8 consecutive k of one col ----
    const int nl  = tid >> 3;                  // 0..63 local col
    const int k8  = (tid & 7) * 8;             // k offset within stage
    const int gcol = colBase + nl;
    const bool colok = (gcol < N);
    const float* bsrc = Bt + (size_t)gcol * KDIM + k8;
    // fragment slot for the LDS write (XOR-swizzled for bank-freedom)
    const int chw = k8 >> 5;                   // k32 chunk within stage (0/1)
    const int kqw = (k8 >> 3) & 3;             // k-octet within chunk
    const int ctw = (nl >> 4) & 3;             // 16-col tile
    const int fidw = chw * 4 + ctw;
    const int lfw  = kqw * 16 + (nl & 15);
    const int slotw = fidw * 64 + (lfw ^ (kqw * 2 + chw));

    floatx4 acc[2][4];
#pragma unroll
    for (int rt = 0; rt < 2; ++rt)
#pragma unroll
        for (int ct = 0; ct < 4; ++ct)
            acc[rt][ct] = (floatx4){0.f, 0.f, 0.f, 0.f};

    const float4 z4 = make_float4(0.f, 0.f, 0.f, 0.f);
    float4 p0 = colok ? *(const float4*)(bsrc)     : z4;
    float4 p1 = colok ? *(const float4*)(bsrc + 4) : z4;

    for (int s = 0; s < NSTAGE; ++s) {
        // convert the prefetched 8 floats to bf16 hi/lo
        union { float4 v[2]; float f[8]; } P;
        union { short8 v; unsigned short u[8]; } H, L;
        P.v[0] = p0; P.v[1] = p1;
#pragma unroll
        for (int j = 0; j < 8; ++j) {
            unsigned short h = f2bf(P.f[j]);
            H.u[j] = h;
            L.u[j] = f2bf(P.f[j] - bf2f(h));
        }
        __syncthreads();                  // previous stage's reads done
        BsH[slotw] = H.v;
        BsL[slotw] = L.v;
        __syncthreads();                  // tile visible

        if (s + 1 < NSTAGE) {             // prefetch next stage during compute
            const float* nsrc = bsrc + (s + 1) * BK;
            p0 = colok ? *(const float4*)(nsrc)     : z4;
            p1 = colok ? *(const float4*)(nsrc + 4) : z4;
        }

#pragma unroll
        for (int chunk = 0; chunk < 2; ++chunk) {
            const int cg = s * 2 + chunk;          // global k32 chunk 0..15
            short8 aH[2], aL[2];
#pragma unroll
            for (int rt = 0; rt < 2; ++rt) {
                const int s16 = wid * 2 + rt;
                size_t sl = (size_t)((s16 * 16 + cg) * 2) * 64 + lane;
                aH[rt] = *(const short8*)(af + sl * 8);
                aL[rt] = *(const short8*)(af + (sl + 64) * 8);
            }
            const int g = (lane >> 4) * 2 + chunk; // reader XOR swizzle
#pragma unroll
            for (int ct = 0; ct < 4; ++ct) {
                const int idx = (chunk * 4 + ct) * 64 + (lane ^ g);
                short8 bh = BsH[idx];
                short8 bl = BsL[idx];
#pragma unroll
                for (int rt = 0; rt < 2; ++rt) {
                    acc[rt][ct] = __builtin_amdgcn_mfma_f32_16x16x32_bf16(aH[rt], bh, acc[rt][ct], 0, 0, 0);
                    acc[rt][ct] = __builtin_amdgcn_mfma_f32_16x16x32_bf16(aH[rt], bl, acc[rt][ct], 0, 0, 0);
                    acc[rt][ct] = __builtin_amdgcn_mfma_f32_16x16x32_bf16(aL[rt], bh, acc[rt][ct], 0, 0, 0);
                }
            }
        }
    }

    // ---- epilogue: chunk max, running global max, candidate append ----
    // C/D layout (verified): col = lane&15, row = (lane>>4)*4 + reg
    const int q   = lane >> 4;
    const int n15 = lane & 15;
#pragma unroll
    for (int rt = 0; rt < 2; ++rt) {
#pragma unroll
        for (int reg = 0; reg < 4; ++reg) {
            const int row = wid * 32 + rt * 16 + q * 4 + reg;
            float m = fmaxf(fmaxf(acc[rt][0][reg], acc[rt][1][reg]),
                            fmaxf(acc[rt][2][reg], acc[rt][3][reg]));
#pragma unroll
            for (int off = 1; off < 16; off <<= 1) m = fmaxf(m, __shfl_xor(m, off));
            unsigned oldk = 0u;
            if (n15 == 0) oldk = atomicMax(&gmax[row], enc_f(m));
            oldk = (unsigned)__shfl((int)oldk, lane & 48);   // quad leader
            const float thr = fmaxf(dec_f(oldk), m) - CUTOFF;
#pragma unroll
            for (int ct = 0; ct < 4; ++ct) {
                const float v = acc[rt][ct][reg];
                const int col = colBase + ct * 16 + n15;
                if (v >= thr && col < N) {
                    unsigned p = atomicAdd(&cnt[row], 1u);
                    if (p < (unsigned)cap) {
                        cand_val[(size_t)row * cap + p] = v;
                        cand_idx[(size_t)row * cap + p] = col;
                    }
                }
            }
        }
    }
}

// One block per row: filter, sort desc, softmax over top-200-equivalent,
// scatter into the 4 k-slices.
__global__ __launch_bounds__(256) void k_finalize(
    const float* __restrict__ cand_val,
    const int* __restrict__ cand_idx,
    const unsigned* __restrict__ cnt,
    const unsigned* __restrict__ gmax,
    const int* __restrict__ labels,
    float* __restrict__ out,
    int Brows, int cap)
{
    __shared__ float s_val[256];
    __shared__ int   s_idx[256];
    __shared__ int   s_n;
    const int row = blockIdx.x;
    const int tid = threadIdx.x;
    if (tid == 0) s_n = 0;
    __syncthreads();

    const float m   = dec_f(gmax[row]);
    const float thr = m - CUTOFF;
    const int n = min((int)cnt[row], cap);
    for (int i = tid; i < n; i += 256) {
        float v = cand_val[(size_t)row * cap + i];
        if (v >= thr) {
            int p = atomicAdd(&s_n, 1);
            if (p < 256) { s_val[p] = v; s_idx[p] = cand_idx[(size_t)row * cap + i]; }
        }
    }
    __syncthreads();

    for (int c = tid; c < 4 * NCLS; c += 256) {
        int s = c / NCLS, cc = c - s * NCLS;
        out[(size_t)s * ((size_t)Brows * NCLS) + (size_t)row * NCLS + cc] = 0.f;
    }
    __syncthreads();

    if (tid == 0) {
        int ns = min(s_n, 256);
        for (int i = 1; i < ns; ++i) {            // tiny insertion sort desc
            float v = s_val[i]; int ix = s_idx[i];
            int j = i - 1;
            while (j >= 0 && s_val[j] < v) { s_val[j+1] = s_val[j]; s_idx[j+1] = s_idx[j]; --j; }
            s_val[j+1] = v; s_idx[j+1] = ix;
        }
        if (ns > 200) ns = 200;
        float Z = 0.f;
        for (int i = 0; i < ns; ++i) Z += expf((s_val[i] - m) / 0.07f);
        float invZ = 1.f / Z;
        const int kv[4] = {10, 20, 100, 200};
        for (int i = 0; i < ns; ++i) {
            float w = expf((s_val[i] - m) / 0.07f) * invZ;
            int lab = labels[s_idx[i]];
#pragma unroll
            for (int s = 0; s < 4; ++s)
                if (i < kv[s])
                    out[(size_t)s * ((size_t)Brows * NCLS) + (size_t)row * NCLS + lab] += w;
        }
    }
}

extern "C" void kernel_launch(void* const* d_in, const int* in_sizes, int n_in,
                              void* d_out, int out_size, void* d_ws, size_t ws_size,
                              hipStream_t stream) {
    const float* A      = (const float*)d_in[0];   // (256, 512)
    const float* Bt     = (const float*)d_in[1];   // (100000, 512)
    const int*   labels = (const int*)d_in[2];     // (100000,)
    float* out = (float*)d_out;                    // (4, 256, 1000)

    const int Brows = in_sizes[0] / KDIM;          // 256
    const int N     = in_sizes[2];                 // 100000

    // ws layout: af (Brows*512*2 bf16 hi+lo) | cnt | gmax | cand_val | cand_idx
    size_t af_elems = (size_t)Brows * KDIM * 2;
    unsigned short* af = (unsigned short*)d_ws;
    unsigned* cnt  = (unsigned*)(af + af_elems);
    unsigned* gmax = cnt + Brows;
    char* rest = (char*)(gmax + Brows);
    size_t used  = (size_t)(rest - (char*)d_ws);
    size_t avail = (ws_size > used) ? (ws_size - used) : 0;
    int cap = (int)((avail / ((size_t)Brows * 8)) < (size_t)MAXCAP
                        ? (avail / ((size_t)Brows * 8)) : (size_t)MAXCAP);
    if (cap < 1) cap = 1;
    float* cand_val = (float*)rest;
    int*   cand_idx = (int*)(cand_val + (size_t)Brows * cap);

    k_prep<<<(Brows * (KDIM / 8) + 255) / 256, 256, 0, stream>>>(A, af, cnt, gmax, Brows);
    k_gemm<<<(N + BN - 1) / BN, 512, 0, stream>>>(Bt, af, cand_val, cand_idx, cnt, gmax, N, cap);
    k_finalize<<<Brows, 256, 0, stream>>>(cand_val, cand_idx, cnt, gmax, labels, out, Brows, cap);
}

// Round 3
// 395.102 us; speedup vs baseline: 7.5494x; 1.0080x over previous
//
#include <hip/hip_runtime.h>
#include <math.h>

#define KDIM   512
#define NCLS   1000
#define CUTOFF 3.0f
#define MAXCAP 4096
#define BN     64
#define BK     64
#define NSTAGE (KDIM / BK)   // 8

typedef __attribute__((ext_vector_type(8))) short  short8;
typedef __attribute__((ext_vector_type(4))) float  floatx4;

// ---- ordered-float <-> uint encoding for atomicMax on floats ----
__device__ __forceinline__ unsigned enc_f(float f) {
    unsigned u = __float_as_uint(f);
    return (u & 0x80000000u) ? ~u : (u | 0x80000000u);
}
__device__ __forceinline__ float dec_f(unsigned k) {
    unsigned u = (k & 0x80000000u) ? (k & 0x7FFFFFFFu) : ~k;
    return __uint_as_float(u);
}
// fp32 -> bf16 round-to-nearest-even
__device__ __forceinline__ unsigned short f2bf(float f) {
    unsigned u = __float_as_uint(f);
    u += 0x7FFFu + ((u >> 16) & 1u);
    return (unsigned short)(u >> 16);
}
__device__ __forceinline__ float bf2f(unsigned short h) {
    return __uint_as_float(((unsigned)h) << 16);
}

// Prep: init cnt/gmax; convert A (Brows x 512 fp32) into fragment-major bf16
// hi/lo: af slot (16B units) = ((s16*16 + c)*2 + h)*64 + lane,
// lane = kq*16 + (r&15), s16 = r>>4, c = k32-chunk, kq = k-octet within chunk.
__global__ void k_prep(const float* __restrict__ A, unsigned short* __restrict__ af,
                       unsigned* __restrict__ cnt, unsigned* __restrict__ gmax, int Brows) {
    int t = blockIdx.x * blockDim.x + threadIdx.x;
    if (t < Brows) { cnt[t] = 0u; gmax[t] = enc_f(-3.0e38f); }
    if (t >= Brows * (KDIM / 8)) return;
    int r = t >> 6;                 // row (64 k-octets per row)
    int o = t & 63;                 // k-octet index
    int s16 = r >> 4, c = o >> 2, kq = o & 3;
    int lane = kq * 16 + (r & 15);
    const float* src = A + (size_t)r * KDIM + o * 8;
    size_t bhi = ((size_t)((s16 * 16 + c) * 2 + 0) * 64 + lane) * 8;
    size_t blo = ((size_t)((s16 * 16 + c) * 2 + 1) * 64 + lane) * 8;
#pragma unroll
    for (int j = 0; j < 8; ++j) {
        float f = src[j];
        unsigned short h = f2bf(f);
        af[bhi + j] = h;
        af[blo + j] = f2bf(f - bf2f(h));
    }
}

// GEMM: block = 512 thr = 8 waves, covers ALL 256 rows (wave w: rows w*32..+32),
// BN=64 cols, full K=512. Split-bf16 3-pass MFMA. Double-buffered LDS (one
// barrier/stage), B-prefetch distance 2, A-frag loads hoisted per chunk.
__global__ __launch_bounds__(512, 4) void k_gemm(
    const float* __restrict__ Bt,            // [N][512] fp32
    const unsigned short* __restrict__ af,   // A frags bf16 hi/lo
    float* __restrict__ cand_val, int* __restrict__ cand_idx,
    unsigned* __restrict__ cnt, unsigned* __restrict__ gmax,
    int N, int cap)
{
    __shared__ short8 BsH[2][512];   // 2 x 8 KB
    __shared__ short8 BsL[2][512];

    const int tid  = threadIdx.x;
    const int lane = tid & 63;
    const int wid  = tid >> 6;                 // 0..7
    const int colBase = blockIdx.x * BN;

    // ---- B staging mapping: thread loads 8 consecutive k of one col ----
    const int nl  = tid >> 3;                  // 0..63 local col
    const int k8  = (tid & 7) * 8;             // k offset within stage
    const int gcol = colBase + nl;
    const bool colok = (gcol < N);
    const float* bsrc = Bt + (size_t)gcol * KDIM + k8;
    const int chw = k8 >> 5;
    const int kqw = (k8 >> 3) & 3;
    const int ctw = (nl >> 4) & 3;
    const int fidw = chw * 4 + ctw;
    const int lfw  = kqw * 16 + (nl & 15);
    const int slotw = fidw * 64 + (lfw ^ (kqw * 2 + chw));

    floatx4 acc[2][4];
#pragma unroll
    for (int rt = 0; rt < 2; ++rt)
#pragma unroll
        for (int ct = 0; ct < 4; ++ct)
            acc[rt][ct] = (floatx4){0.f, 0.f, 0.f, 0.f};

    const float4 z4 = make_float4(0.f, 0.f, 0.f, 0.f);
    // c = stage-0 data (to convert now); n = stage-1 data (in flight)
    float4 c0 = colok ? *(const float4*)(bsrc)          : z4;
    float4 c1 = colok ? *(const float4*)(bsrc + 4)      : z4;
    float4 n0 = colok ? *(const float4*)(bsrc + BK)     : z4;
    float4 n1 = colok ? *(const float4*)(bsrc + BK + 4) : z4;

    // convert + write stage 0 into buf 0
    {
        union { float4 v[2]; float f[8]; } P;
        union { short8 v; unsigned short u[8]; } H, L;
        P.v[0] = c0; P.v[1] = c1;
#pragma unroll
        for (int j = 0; j < 8; ++j) {
            unsigned short h = f2bf(P.f[j]);
            H.u[j] = h; L.u[j] = f2bf(P.f[j] - bf2f(h));
        }
        BsH[0][slotw] = H.v; BsL[0][slotw] = L.v;
    }
    __syncthreads();

    for (int s = 0; s < NSTAGE; ++s) {
        // ---- stage s+1: move regs, issue prefetch of s+2, convert, LDS write ----
        if (s + 1 < NSTAGE) {
            c0 = n0; c1 = n1;
            if (s + 2 < NSTAGE) {
                const float* p = bsrc + (s + 2) * BK;
                n0 = colok ? *(const float4*)(p)     : z4;
                n1 = colok ? *(const float4*)(p + 4) : z4;
            }
            union { float4 v[2]; float f[8]; } P;
            union { short8 v; unsigned short u[8]; } H, L;
            P.v[0] = c0; P.v[1] = c1;
#pragma unroll
            for (int j = 0; j < 8; ++j) {
                unsigned short h = f2bf(P.f[j]);
                H.u[j] = h; L.u[j] = f2bf(P.f[j] - bf2f(h));
            }
            BsH[(s + 1) & 1][slotw] = H.v; BsL[(s + 1) & 1][slotw] = L.v;
        }

        // ---- compute stage s from buf[s&1] ----
#pragma unroll
        for (int chunk = 0; chunk < 2; ++chunk) {
            const int cg = s * 2 + chunk;          // global k32 chunk
            short8 aH[2], aL[2];
#pragma unroll
            for (int rt = 0; rt < 2; ++rt) {       // hoisted ahead of MFMAs
                const int s16 = wid * 2 + rt;
                size_t sl = (size_t)((s16 * 16 + cg) * 2) * 64 + lane;
                aH[rt] = *(const short8*)(af + sl * 8);
                aL[rt] = *(const short8*)(af + (sl + 64) * 8);
            }
            const int g = (lane >> 4) * 2 + chunk; // reader XOR swizzle
#pragma unroll
            for (int ct = 0; ct < 4; ++ct) {
                const int idx = (chunk * 4 + ct) * 64 + (lane ^ g);
                short8 bh = BsH[s & 1][idx];
                short8 bl = BsL[s & 1][idx];
#pragma unroll
                for (int rt = 0; rt < 2; ++rt) {
                    acc[rt][ct] = __builtin_amdgcn_mfma_f32_16x16x32_bf16(aH[rt], bh, acc[rt][ct], 0, 0, 0);
                    acc[rt][ct] = __builtin_amdgcn_mfma_f32_16x16x32_bf16(aH[rt], bl, acc[rt][ct], 0, 0, 0);
                    acc[rt][ct] = __builtin_amdgcn_mfma_f32_16x16x32_bf16(aL[rt], bh, acc[rt][ct], 0, 0, 0);
                }
            }
        }
        __syncthreads();
    }

    // ---- epilogue: chunk max, running global max, candidate append ----
    // C/D layout (verified): col = lane&15, row = (lane>>4)*4 + reg
    const int q   = lane >> 4;
    const int n15 = lane & 15;
#pragma unroll
    for (int rt = 0; rt < 2; ++rt) {
#pragma unroll
        for (int reg = 0; reg < 4; ++reg) {
            const int row = wid * 32 + rt * 16 + q * 4 + reg;
            float m = fmaxf(fmaxf(acc[rt][0][reg], acc[rt][1][reg]),
                            fmaxf(acc[rt][2][reg], acc[rt][3][reg]));
#pragma unroll
            for (int off = 1; off < 16; off <<= 1) m = fmaxf(m, __shfl_xor(m, off));
            unsigned oldk = 0u;
            if (n15 == 0) oldk = atomicMax(&gmax[row], enc_f(m));
            oldk = (unsigned)__shfl((int)oldk, lane & 48);   // quad leader
            const float thr = fmaxf(dec_f(oldk), m) - CUTOFF;
#pragma unroll
            for (int ct = 0; ct < 4; ++ct) {
                const float v = acc[rt][ct][reg];
                const int col = colBase + ct * 16 + n15;
                if (v >= thr && col < N) {
                    unsigned p = atomicAdd(&cnt[row], 1u);
                    if (p < (unsigned)cap) {
                        cand_val[(size_t)row * cap + p] = v;
                        cand_idx[(size_t)row * cap + p] = col;
                    }
                }
            }
        }
    }
}

// One block per row: filter, sort desc, softmax over top-200-equivalent,
// scatter into the 4 k-slices.
__global__ __launch_bounds__(256) void k_finalize(
    const float* __restrict__ cand_val,
    const int* __restrict__ cand_idx,
    const unsigned* __restrict__ cnt,
    const unsigned* __restrict__ gmax,
    const int* __restrict__ labels,
    float* __restrict__ out,
    int Brows, int cap)
{
    __shared__ float s_val[256];
    __shared__ int   s_idx[256];
    __shared__ int   s_n;
    const int row = blockIdx.x;
    const int tid = threadIdx.x;
    if (tid == 0) s_n = 0;
    __syncthreads();

    const float m   = dec_f(gmax[row]);
    const float thr = m - CUTOFF;
    const int n = min((int)cnt[row], cap);
    for (int i = tid; i < n; i += 256) {
        float v = cand_val[(size_t)row * cap + i];
        if (v >= thr) {
            int p = atomicAdd(&s_n, 1);
            if (p < 256) { s_val[p] = v; s_idx[p] = cand_idx[(size_t)row * cap + i]; }
        }
    }
    __syncthreads();

    for (int c = tid; c < 4 * NCLS; c += 256) {
        int s = c / NCLS, cc = c - s * NCLS;
        out[(size_t)s * ((size_t)Brows * NCLS) + (size_t)row * NCLS + cc] = 0.f;
    }
    __syncthreads();

    if (tid == 0) {
        int ns = min(s_n, 256);
        for (int i = 1; i < ns; ++i) {            // tiny insertion sort desc
            float v = s_val[i]; int ix = s_idx[i];
            int j = i - 1;
            while (j >= 0 && s_val[j] < v) { s_val[j+1] = s_val[j]; s_idx[j+1] = s_idx[j]; --j; }
            s_val[j+1] = v; s_idx[j+1] = ix;
        }
        if (ns > 200) ns = 200;
        float Z = 0.f;
        for (int i = 0; i < ns; ++i) Z += expf((s_val[i] - m) / 0.07f);
        float invZ = 1.f / Z;
        const int kv[4] = {10, 20, 100, 200};
        for (int i = 0; i < ns; ++i) {
            float w = expf((s_val[i] - m) / 0.07f) * invZ;
            int lab = labels[s_idx[i]];
#pragma unroll
            for (int s = 0; s < 4; ++s)
                if (i < kv[s])
                    out[(size_t)s * ((size_t)Brows * NCLS) + (size_t)row * NCLS + lab] += w;
        }
    }
}

extern "C" void kernel_launch(void* const* d_in, const int* in_sizes, int n_in,
                              void* d_out, int out_size, void* d_ws, size_t ws_size,
                              hipStream_t stream) {
    const float* A      = (const float*)d_in[0];   // (256, 512)
    const float* Bt     = (const float*)d_in[1];   // (100000, 512)
    const int*   labels = (const int*)d_in[2];     // (100000,)
    float* out = (float*)d_out;                    // (4, 256, 1000)

    const int Brows = in_sizes[0] / KDIM;          // 256
    const int N     = in_sizes[2];                 // 100000

    // ws layout: af (Brows*512*2 bf16 hi+lo) | cnt | gmax | cand_val | cand_idx
    size_t af_elems = (size_t)Brows * KDIM * 2;
    unsigned short* af = (unsigned short*)d_ws;
    unsigned* cnt  = (unsigned*)(af + af_elems);
    unsigned* gmax = cnt + Brows;
    char* rest = (char*)(gmax + Brows);
    size_t used  = (size_t)(rest - (char*)d_ws);
    size_t avail = (ws_size > used) ? (ws_size - used) : 0;
    int cap = (int)((avail / ((size_t)Brows * 8)) < (size_t)MAXCAP
                        ? (avail / ((size_t)Brows * 8)) : (size_t)MAXCAP);
    if (cap < 1) cap = 1;
    float* cand_val = (float*)rest;
    int*   cand_idx = (int*)(cand_val + (size_t)Brows * cap);

    k_prep<<<(Brows * (KDIM / 8) + 255) / 256, 256, 0, stream>>>(A, af, cnt, gmax, Brows);
    k_gemm<<<(N + BN - 1) / BN, 512, 0, stream>>>(Bt, af, cand_val, cand_idx, cnt, gmax, N, cap);
    k_finalize<<<Brows, 256, 0, stream>>>(cand_val, cand_idx, cnt, gmax, labels, out, Brows, cap);
}